// Round 9
// baseline (162.841 us; speedup 1.0000x reference)
//
#include <hip/hip_runtime.h>
#include <hip/hip_bf16.h>

#define NEG_SLOPE 0.2f
#define INV_LN2 1.44269504088896340736f
#define BSH   6        // bucket = 64 dst nodes
#define BUKSZ 64
#define MAXBUK 1024    // supports N <= 65536 (src ids fit in ushort)
#define CHUNK 2048     // edges per partition block (391 blocks for E=800000)
#define CAP   2048     // fixed per-bucket capacity (mean 1023, sigma 32 -> 30σ)
#define CAPSH 11
#define XPAD  136      // LDS row stride (128 + 8): 272 B rows, 16B-aligned

typedef __attribute__((ext_vector_type(8))) short bf16x8;   // 8 bf16 = 4 VGPRs
typedef __attribute__((ext_vector_type(4))) float f32x4;    // MFMA C/D

// exp(lrelu(z)) where z is PRE-SCALED by 1/ln2 (lrelu positively homogeneous).
__device__ __forceinline__ float exp2lrelu(float z) {
    return __builtin_amdgcn_exp2f(fmaxf(z, NEG_SLOPE * z));
}

__device__ __forceinline__ unsigned short f2bf(float f) {   // RNE float->bf16
    unsigned int u = __float_as_uint(f);
    u = (u + 0x7fffu + ((u >> 16) & 1u)) >> 16;
    return (unsigned short)u;
}

__device__ __forceinline__ float2 bfpair(unsigned int u) {  // 2 packed bf16 -> 2 floats
    float2 r;
    r.x = __uint_as_float(u << 16);
    r.y = __uint_as_float(u & 0xffff0000u);
    return r;
}

// ---------------------------------------------------------------------------
// K0_PREP: zero gcur + build extended B matrix w1t[144][128] bf16:
//   rows   0..127 : W1^T
//   rows 128..131 : (W1 @ a_src1)^T * 1/ln2   (GEMM col -> a_s1)
//   rows 132..135 : (W1 @ a_dst1)^T * 1/ln2   (GEMM col -> a_d1)
//   rows 136..143 : zeros (pad to full 16-col MFMA tile)
// ---------------------------------------------------------------------------
__global__ __launch_bounds__(256) void k0_prep(const float* __restrict__ W1,
                                               const float* __restrict__ a_src1,
                                               const float* __restrict__ a_dst1,
                                               unsigned short* __restrict__ w1t,
                                               int* __restrict__ gcur, int nbuk) {
    int g = blockIdx.x * 256 + threadIdx.x;
    if (g < nbuk) gcur[g] = 0;
    if (g < 128 * 128) {
        int k = g >> 7, nn = g & 127;        // coalesced W1 read
        w1t[nn * 128 + k] = f2bf(W1[g]);
    } else if (g < 128 * 128 + 1024) {
        int e = g - 128 * 128;               // 0..1023
        int row8 = e >> 7;                   // 0-3 = a_src heads, 4-7 = a_dst
        int k = e & 127;
        int h = row8 & 3;
        const float* av = (row8 < 4) ? a_src1 : a_dst1;
        float s = 0.f;
#pragma unroll
        for (int c = 0; c < 32; ++c)
            s += W1[k * 128 + h * 32 + c] * av[h * 32 + c];
        w1t[(128 + row8) * 128 + k] = f2bf(s * INV_LN2);
    } else if (g < 128 * 128 + 2048) {
        int e = g - (128 * 128 + 1024);
        w1t[(136 + (e >> 7)) * 128 + (e & 127)] = 0;
    }
}

// ---------------------------------------------------------------------------
// K1_FAT: blocks [0, nblk): BARRIER-FREE partition into fixed-capacity
// buckets: LDS chunk-hist -> ONE atomicAdd(&gcur[b],cnt) reservation per
// non-empty bucket (disjoint ranges, no ordering needed) -> bounds-guarded
// scatter into part[b*CAP ...]. Fully hidden under blocks [nblk, ...):
// MFMA GEMM [h1b | a_s1 | a_d1] = x @ [W1 | aw_s | aw_d] (9 n-tiles),
// A-fragments direct from global x, wsh reused for h1b output staging.
// (R4/R6 lesson: a 391-block spin barrier costs ~180us on this chip — the
// polling storm starves the serialized arrival RMWs. Fixed-cap buckets
// remove the need for the pre-scatter barrier entirely.)
// ---------------------------------------------------------------------------
__global__ __launch_bounds__(256) void k1_fat(const float* __restrict__ x,
                                              const unsigned short* __restrict__ w1t,
                                              unsigned short* __restrict__ h1b,
                                              float* __restrict__ a_s1,
                                              float* __restrict__ a_d1, int n,
                                              const int* __restrict__ e_src,
                                              const int* __restrict__ e_dst, int e,
                                              int nbuk, int nblk,
                                              int* __restrict__ gcur,
                                              unsigned int* __restrict__ part) {
    __shared__ unsigned short wsh[144 * XPAD];   // extended W^T bf16 (39.2 KB)
    const int tid = threadIdx.x;

    if (blockIdx.x < (unsigned)nblk) {
        // ================= partition (no barriers) =================
        int* lcur = (int*)wsh;                   // [MAXBUK] hist -> cursors
        const int bid = blockIdx.x;
        const int e0 = bid * CHUNK;
        const int e1 = min(e, e0 + CHUNK);
        for (int b = tid; b < nbuk; b += 256) lcur[b] = 0;
        __syncthreads();
        for (int k = e0 + tid; k < e1; k += 256)
            atomicAdd(&lcur[e_dst[k] >> BSH], 1);
        __syncthreads();
        // batch reservation into this bucket's FIXED region [b*CAP, (b+1)*CAP)
        for (int b = tid; b < nbuk; b += 256) {
            int c = lcur[b];
            if (c) lcur[b] = (b << CAPSH) + atomicAdd(&gcur[b], c);
        }
        __syncthreads();
        for (int k = e0 + tid; k < e1; k += 256) {
            int d = e_dst[k];
            int b = d >> BSH;
            int pos = atomicAdd(&lcur[b], 1);
            if (pos < ((b + 1) << CAPSH))        // 30-sigma guard, no OOB
                part[pos] = ((unsigned int)e_src[k] << 16) | (unsigned int)(d & 0xffff);
        }
        return;
    }

    // ================= GEMM path =================
    const int row0 = (blockIdx.x - nblk) * 64;
    // stage w1t -> wsh[n*XPAD+k]: 2304 ushort8 vector copies (9 per thread)
    {
        const bf16x8* w1v = (const bf16x8*)w1t;
#pragma unroll
        for (int ii = 0; ii < 9; ++ii) {
            int i = tid + ii * 256;
            int r = i >> 4, c = (i & 15) * 8;
            *(bf16x8*)&wsh[r * XPAD + c] = w1v[i];
        }
    }

    const int wave = tid >> 6;
    const int lane = tid & 63;
    const int quad = lane >> 4;
    const int l16 = lane & 15;

    // A fragments direct from global: row = row0 + wave*16 + l16,
    // k = ks*32 + quad*8 .. +7 (8 contiguous fp32 -> bf16x8)
    const int arow = row0 + wave * 16 + l16;
    const bool rowok = arow < n;
    const float* __restrict__ xr = x + (size_t)arow * 128;
    bf16x8 afrag[4];
#pragma unroll
    for (int ks = 0; ks < 4; ++ks) {
        float4 u = make_float4(0.f, 0.f, 0.f, 0.f), v = u;
        if (rowok) {
            u = *(const float4*)&xr[ks * 32 + quad * 8];
            v = *(const float4*)&xr[ks * 32 + quad * 8 + 4];
        }
        bf16x8 a;
        a[0] = (short)f2bf(u.x); a[1] = (short)f2bf(u.y);
        a[2] = (short)f2bf(u.z); a[3] = (short)f2bf(u.w);
        a[4] = (short)f2bf(v.x); a[5] = (short)f2bf(v.y);
        a[6] = (short)f2bf(v.z); a[7] = (short)f2bf(v.w);
        afrag[ks] = a;
    }
    __syncthreads();                      // wsh staged

    f32x4 acc[9];
#pragma unroll
    for (int t = 0; t < 9; ++t) acc[t] = (f32x4){0.f, 0.f, 0.f, 0.f};

#pragma unroll
    for (int t = 0; t < 9; ++t) {
#pragma unroll
        for (int ks = 0; ks < 4; ++ks) {
            bf16x8 bfrag = *(const bf16x8*)&wsh[(t * 16 + l16) * XPAD + ks * 32 + quad * 8];
            acc[t] = __builtin_amdgcn_mfma_f32_16x16x32_bf16(afrag[ks], bfrag, acc[t], 0, 0, 0);
        }
    }

    // tile 8: cols 0-3 = a_s heads, 4-7 = a_d (already INV_LN2-scaled)
#pragma unroll
    for (int r = 0; r < 4; ++r) {
        int gr = row0 + wave * 16 + quad * 4 + r;
        if (gr < n) {
            if (l16 < 4)      a_s1[gr * 4 + l16]       = acc[8][r];
            else if (l16 < 8) a_d1[gr * 4 + (l16 - 4)] = acc[8][r];
        }
    }

    // h1b store via LDS: reuse wsh (dead after MFMAs) as 64-row staging
    __syncthreads();                      // all waves done reading wsh
#pragma unroll
    for (int t = 0; t < 8; ++t)
#pragma unroll
        for (int r = 0; r < 4; ++r)
            wsh[(wave * 16 + quad * 4 + r) * XPAD + t * 16 + l16] = f2bf(acc[t][r]);
    __syncthreads();
#pragma unroll
    for (int i = 0; i < 8; ++i) {
        int idx = tid + i * 256;          // ushort4 index 0..2047 (32 per row)
        int r = idx >> 5;
        int c = (idx & 31) * 4;
        int gr = row0 + r;
        if (gr < n)
            *(ushort4*)&h1b[(size_t)gr * 128 + c] = *(ushort4*)&wsh[r * XPAD + c];
    }
}

// ---------------------------------------------------------------------------
// KC_CSR: block per bucket (fixed region [b*CAP, b*CAP+gcur[b])) ->
// rsd[node] = (absolute csr start, degree) int2 + csr_src (ushort).
// Two passes over part (count, then direct 2B scatter, L2-merged).
// ---------------------------------------------------------------------------
__global__ __launch_bounds__(256) void kc_csr(const unsigned int* __restrict__ part,
                                              const int* __restrict__ gcur, int nbuk,
                                              int2* __restrict__ rsd,
                                              unsigned short* __restrict__ csr_src) {
    __shared__ int cnt[64];
    __shared__ int cur[64];
    const int b = blockIdx.x;
    const int tid = threadIdx.x;
    const int eb = b << CAPSH;
    const int nE = min(gcur[b], CAP);
    if (tid < 64) cnt[tid] = 0;
    __syncthreads();
    for (int k = tid; k < nE; k += 256)
        atomicAdd(&cnt[part[eb + k] & 63u], 1);
    __syncthreads();
    if (tid < 64) {                       // wave-0 exclusive scan of 64 counts
        int v = cnt[tid];
        int incl = v;
#pragma unroll
        for (int off = 1; off < 64; off <<= 1) {
            int t = __shfl_up(incl, off);
            if (tid >= off) incl += t;
        }
        cur[tid] = incl - v;
        rsd[(b << BSH) + tid] = make_int2(eb + incl - v, v);
    }
    __syncthreads();
    for (int k = tid; k < nE; k += 256) {
        unsigned int u = part[eb + k];
        int pos = atomicAdd(&cur[u & 63u], 1);
        csr_src[eb + pos] = (unsigned short)(u >> 16);   // 2B scatter, L2-merged
    }
}

// ---------------------------------------------------------------------------
// K3: layer-1 softmax-aggregation, one wave per dst node. deg is wave-uniform.
// Bulk: UNPREDICATED 16-slot iters (4 gather chains/lane, max MLP).
// Tail: 4-slot mini-iters (1 gather chain/lane) — with mean deg ~17, the old
// 16-slot predicated tail wasted ~half of k3's VALU issue on empty slots;
// 4-slot granularity cuts mean tail cost ~45%.
// Fused: +bias, relu, layer-2 proj, layer-2 dots.
// ---------------------------------------------------------------------------
__global__ __launch_bounds__(256) void k3_agg1(
    const unsigned short* __restrict__ h1b, const float* __restrict__ a_s1,
    const float* __restrict__ a_d1, const int2* __restrict__ rsd,
    const unsigned short* __restrict__ csr_src, const float* __restrict__ b1,
    const float* __restrict__ W2, const float* __restrict__ a_src2,
    const float* __restrict__ a_dst2, float4* __restrict__ pk, int n) {
    const int wid = (blockIdx.x * blockDim.x + threadIdx.x) >> 6;
    const int lane = threadIdx.x & 63;
    if (wid >= n) return;
    const int q = lane >> 4;             // quarter: edge slot 0..3
    const int l16 = lane & 15;
    const int c0 = l16 * 8;              // 8 channels per lane
    const unsigned cb = (unsigned)l16 * 16u;   // byte offset within row
    const int head = l16 >> 2;           // 4 lanes per head
    const int2 rd = rsd[wid];
    const int rs = rd.x;
    const int deg = rd.y;
    const float ad = a_d1[wid * 4 + head];
    const char* __restrict__ h1c = (const char*)h1b;
    const unsigned short* __restrict__ crs = csr_src + rs;

    float dnm = 0.f;
    float acc[8] = {};
    const int nfull = deg >> 4;
    const int dm1 = deg - 1;
    int j = q;
    for (int it = 0; it < nfull; ++it, j += 16) {   // unpredicated full iters
        unsigned s0 = (unsigned)crs[j];
        unsigned s1 = (unsigned)crs[j + 4];
        unsigned s2 = (unsigned)crs[j + 8];
        unsigned s3 = (unsigned)crs[j + 12];
        float as0 = a_s1[(s0 << 2) + head];
        float as1 = a_s1[(s1 << 2) + head];
        float as2 = a_s1[(s2 << 2) + head];
        float as3 = a_s1[(s3 << 2) + head];
        uint4 g0 = *(const uint4*)(h1c + ((s0 << 8) + cb));
        uint4 g1 = *(const uint4*)(h1c + ((s1 << 8) + cb));
        uint4 g2 = *(const uint4*)(h1c + ((s2 << 8) + cb));
        uint4 g3 = *(const uint4*)(h1c + ((s3 << 8) + cb));
        float p0 = exp2lrelu(as0 + ad);
        float p1 = exp2lrelu(as1 + ad);
        float p2 = exp2lrelu(as2 + ad);
        float p3 = exp2lrelu(as3 + ad);
        dnm += (p0 + p1) + (p2 + p3);
        float2 v0a = bfpair(g0.x), v0b = bfpair(g0.y), v0c = bfpair(g0.z), v0d = bfpair(g0.w);
        float2 v1a = bfpair(g1.x), v1b = bfpair(g1.y), v1c = bfpair(g1.z), v1d = bfpair(g1.w);
        float2 v2a = bfpair(g2.x), v2b = bfpair(g2.y), v2c = bfpair(g2.z), v2d = bfpair(g2.w);
        float2 v3a = bfpair(g3.x), v3b = bfpair(g3.y), v3c = bfpair(g3.z), v3d = bfpair(g3.w);
        acc[0] += (p0 * v0a.x + p1 * v1a.x) + (p2 * v2a.x + p3 * v3a.x);
        acc[1] += (p0 * v0a.y + p1 * v1a.y) + (p2 * v2a.y + p3 * v3a.y);
        acc[2] += (p0 * v0b.x + p1 * v1b.x) + (p2 * v2b.x + p3 * v3b.x);
        acc[3] += (p0 * v0b.y + p1 * v1b.y) + (p2 * v2b.y + p3 * v3b.y);
        acc[4] += (p0 * v0c.x + p1 * v1c.x) + (p2 * v2c.x + p3 * v3c.x);
        acc[5] += (p0 * v0c.y + p1 * v1c.y) + (p2 * v2c.y + p3 * v3c.y);
        acc[6] += (p0 * v0d.x + p1 * v1d.x) + (p2 * v2d.x + p3 * v3d.x);
        acc[7] += (p0 * v0d.y + p1 * v1d.y) + (p2 * v2d.y + p3 * v3d.y);
    }
    // 4-slot mini-tail: each iter handles slots t..t+3 (lane's slot = t+q)
    for (int t = nfull << 4; t < deg; t += 4) {
        const int slot = t + q;
        const bool b0 = slot < deg;
        unsigned s0 = (unsigned)crs[min(slot, dm1)];
        float as0 = a_s1[(s0 << 2) + head];
        uint4 g0 = make_uint4(0, 0, 0, 0);
        if (b0) g0 = *(const uint4*)(h1c + ((s0 << 8) + cb));
        float p0 = b0 ? exp2lrelu(as0 + ad) : 0.f;
        dnm += p0;
        float2 va = bfpair(g0.x), vb = bfpair(g0.y), vc = bfpair(g0.z), vd = bfpair(g0.w);
        acc[0] += p0 * va.x;  acc[1] += p0 * va.y;
        acc[2] += p0 * vb.x;  acc[3] += p0 * vb.y;
        acc[4] += p0 * vc.x;  acc[5] += p0 * vc.y;
        acc[6] += p0 * vd.x;  acc[7] += p0 * vd.y;
    }
    // combine quarters
    dnm += __shfl_xor(dnm, 16);
    dnm += __shfl_xor(dnm, 32);
#pragma unroll
    for (int k = 0; k < 8; ++k) {
        acc[k] += __shfl_xor(acc[k], 16);
        acc[k] += __shfl_xor(acc[k], 32);
    }
    // self-loop (uniform across quarters)
    {
        float p = exp2lrelu(a_s1[wid * 4 + head] + ad);
        uint4 gs = *(const uint4*)(h1c + (((unsigned)wid << 8) + cb));
        float2 ha = bfpair(gs.x), hb = bfpair(gs.y), hc = bfpair(gs.z), hd2 = bfpair(gs.w);
        dnm += p;
        acc[0] += p * ha.x;  acc[1] += p * ha.y;
        acc[2] += p * hb.x;  acc[3] += p * hb.y;
        acc[4] += p * hc.x;  acc[5] += p * hc.y;
        acc[6] += p * hd2.x; acc[7] += p * hd2.y;
    }
    float inv = 1.f / (dnm + 1e-16f);
    float r[8];
    float4 bva = *(const float4*)&b1[c0];
    float4 bvb = *(const float4*)&b1[c0 + 4];
    r[0] = fmaxf(acc[0] * inv + bva.x, 0.f);
    r[1] = fmaxf(acc[1] * inv + bva.y, 0.f);
    r[2] = fmaxf(acc[2] * inv + bva.z, 0.f);
    r[3] = fmaxf(acc[3] * inv + bva.w, 0.f);
    r[4] = fmaxf(acc[4] * inv + bvb.x, 0.f);
    r[5] = fmaxf(acc[5] * inv + bvb.y, 0.f);
    r[6] = fmaxf(acc[6] * inv + bvb.z, 0.f);
    r[7] = fmaxf(acc[7] * inv + bvb.w, 0.f);

    // fused layer-2 projection
    float p0 = 0.f, p1 = 0.f;
#pragma unroll
    for (int k = 0; k < 4; ++k) {
        float4 w = *(const float4*)&W2[c0 * 2 + k * 4];
        p0 += r[2 * k] * w.x + r[2 * k + 1] * w.z;
        p1 += r[2 * k] * w.y + r[2 * k + 1] * w.w;
    }
#pragma unroll
    for (int off = 1; off < 16; off <<= 1) {
        p0 += __shfl_xor(p0, off);
        p1 += __shfl_xor(p1, off);
    }
    if (lane == 0) {
        pk[wid] = make_float4(p0, p1,
                              (p0 * a_src2[0] + p1 * a_src2[1]) * INV_LN2,
                              (p0 * a_dst2[0] + p1 * a_dst2[1]) * INV_LN2);
    }
}

// ---------------------------------------------------------------------------
// K4: layer-2 softmax-aggregation (1 head, 2 ch) + bias + log_softmax.
// ---------------------------------------------------------------------------
__global__ __launch_bounds__(256) void k4_agg2(
    const float4* __restrict__ pk, const int2* __restrict__ rsd,
    const unsigned short* __restrict__ csr_src, const float* __restrict__ b2,
    float* __restrict__ out, int n) {
    const int g = blockIdx.x * blockDim.x + threadIdx.x;
    const int lane = threadIdx.x & 63;
    const int node = (g >> 6) * 4 + (lane >> 4);
    const int l16 = lane & 15;
    if (node >= n) return;
    const int2 rd = rsd[node];
    const int rs = rd.x;
    const int deg = rd.y;
    const float4 me = pk[node];
    const float ad = me.w;

    float dnm = 0.f, a0 = 0.f, a1 = 0.f;
    for (int j = l16; j < deg; j += 16) {
        int s = (int)csr_src[rs + j];
        float4 qv = pk[s];
        float p = exp2lrelu(qv.z + ad);
        dnm += p;
        a0 += p * qv.x;
        a1 += p * qv.y;
    }
    if (l16 == 0) {   // self-loop
        float p = exp2lrelu(me.z + ad);
        dnm += p;
        a0 += p * me.x;
        a1 += p * me.y;
    }
#pragma unroll
    for (int off = 1; off < 16; off <<= 1) {
        dnm += __shfl_xor(dnm, off);
        a0 += __shfl_xor(a0, off);
        a1 += __shfl_xor(a1, off);
    }
    if (l16 == 0) {
        float inv = 1.f / (dnm + 1e-16f);
        float o0 = a0 * inv + b2[0];
        float o1 = a1 * inv + b2[1];
        float m2 = fmaxf(o0, o1);
        float lse = m2 + logf(__expf(o0 - m2) + __expf(o1 - m2));
        out[node * 2 + 0] = o0 - lse;
        out[node * 2 + 1] = o1 - lse;
    }
}

// ---------------------------------------------------------------------------
extern "C" void kernel_launch(void* const* d_in, const int* in_sizes, int n_in,
                              void* d_out, int out_size, void* d_ws, size_t ws_size,
                              hipStream_t stream) {
    const float* x      = (const float*)d_in[0];
    const int*   ei     = (const int*)d_in[1];
    const float* W1     = (const float*)d_in[2];
    const float* a_src1 = (const float*)d_in[3];
    const float* a_dst1 = (const float*)d_in[4];
    const float* b1     = (const float*)d_in[5];
    const float* W2     = (const float*)d_in[6];
    const float* a_src2 = (const float*)d_in[7];
    const float* a_dst2 = (const float*)d_in[8];
    const float* b2     = (const float*)d_in[9];
    float* out = (float*)d_out;

    const int N = in_sizes[0] / 128;
    const int E = in_sizes[1] / 2;
    const int* e_src = ei;        // edge_index[0]
    const int* e_dst = ei + E;    // edge_index[1]

    const int NBUK = (N + BUKSZ - 1) >> BSH;     // 782 for N=50000
    const int nblk = (E + CHUNK - 1) / CHUNK;    // 391 for E=800000
    const int gemmBlocks = (N + 63) / 64;        // 782

    // ---- workspace carve (256B aligned)
    char* p = (char*)d_ws;
    auto alloc = [&](size_t bytes) -> void* {
        void* r = (void*)p;
        p += (bytes + 255) & ~(size_t)255;
        return r;
    };
    unsigned short* h1b   = (unsigned short*)alloc((size_t)N * 128 * 2);
    float*          a_s1  = (float*)alloc((size_t)N * 4 * 4);
    float*          a_d1  = (float*)alloc((size_t)N * 4 * 4);
    float4*         pk    = (float4*)alloc((size_t)N * 16);
    unsigned short* w1t   = (unsigned short*)alloc((size_t)144 * 128 * 2);
    int*            gcur  = (int*)alloc((size_t)NBUK * 4);
    unsigned int*   part  = (unsigned int*)alloc((size_t)NBUK * CAP * 4);
    int2*           rsd   = (int2*)alloc((size_t)(NBUK << BSH) * 8);
    unsigned short* csr_src = (unsigned short*)alloc((size_t)NBUK * CAP * 2);

    k0_prep<<<72, 256, 0, stream>>>(W1, a_src1, a_dst1, w1t, gcur, NBUK);
    k1_fat<<<nblk + gemmBlocks, 256, 0, stream>>>(x, w1t, h1b, a_s1, a_d1, N,
                                                  e_src, e_dst, E, NBUK, nblk,
                                                  gcur, part);
    kc_csr<<<NBUK, 256, 0, stream>>>(part, gcur, NBUK, rsd, csr_src);
    k3_agg1<<<(N * 64 + 255) / 256, 256, 0, stream>>>(h1b, a_s1, a_d1, rsd, csr_src,
                                                      b1, W2, a_src2, a_dst2, pk, N);
    k4_agg2<<<((N + 3) / 4 * 64 + 255) / 256, 256, 0, stream>>>(pk, rsd, csr_src,
                                                                b2, out, N);
}

// Round 10
// 162.419 us; speedup vs baseline: 1.0026x; 1.0026x over previous
//
#include <hip/hip_runtime.h>
#include <hip/hip_bf16.h>

#define NEG_SLOPE 0.2f
#define INV_LN2 1.44269504088896340736f
#define BSH   6        // bucket = 64 dst nodes
#define BUKSZ 64
#define MAXBUK 1024    // supports N <= 65536 (src ids fit in ushort)
#define CHUNK 2048     // edges per partition block (391 blocks for E=800000)
#define CAP   2048     // fixed per-bucket capacity (mean 1023, sigma 32 -> 30σ)
#define CAPSH 11
#define XPAD  136      // LDS row stride (128 + 8): 272 B rows, 16B-aligned

typedef __attribute__((ext_vector_type(8))) short bf16x8;   // 8 bf16 = 4 VGPRs
typedef __attribute__((ext_vector_type(4))) float f32x4;    // MFMA C/D

// exp(lrelu(z)) where z is PRE-SCALED by 1/ln2 (lrelu positively homogeneous).
__device__ __forceinline__ float exp2lrelu(float z) {
    return __builtin_amdgcn_exp2f(fmaxf(z, NEG_SLOPE * z));
}

__device__ __forceinline__ unsigned short f2bf(float f) {   // RNE float->bf16
    unsigned int u = __float_as_uint(f);
    u = (u + 0x7fffu + ((u >> 16) & 1u)) >> 16;
    return (unsigned short)u;
}

__device__ __forceinline__ float2 bfpair(unsigned int u) {  // 2 packed bf16 -> 2 floats
    float2 r;
    r.x = __uint_as_float(u << 16);
    r.y = __uint_as_float(u & 0xffff0000u);
    return r;
}

// ---------------------------------------------------------------------------
// K0_PREP: zero gcur + build extended B matrix w1t[144][128] bf16:
//   rows   0..127 : W1^T
//   rows 128..131 : (W1 @ a_src1)^T * 1/ln2   (GEMM col -> a_s1)
//   rows 132..135 : (W1 @ a_dst1)^T * 1/ln2   (GEMM col -> a_d1)
//   rows 136..143 : zeros (pad to full 16-col MFMA tile)
// ---------------------------------------------------------------------------
__global__ __launch_bounds__(256) void k0_prep(const float* __restrict__ W1,
                                               const float* __restrict__ a_src1,
                                               const float* __restrict__ a_dst1,
                                               unsigned short* __restrict__ w1t,
                                               int* __restrict__ gcur, int nbuk) {
    int g = blockIdx.x * 256 + threadIdx.x;
    if (g < nbuk) gcur[g] = 0;
    if (g < 128 * 128) {
        int k = g >> 7, nn = g & 127;        // coalesced W1 read
        w1t[nn * 128 + k] = f2bf(W1[g]);
    } else if (g < 128 * 128 + 1024) {
        int e = g - 128 * 128;               // 0..1023
        int row8 = e >> 7;                   // 0-3 = a_src heads, 4-7 = a_dst
        int k = e & 127;
        int h = row8 & 3;
        const float* av = (row8 < 4) ? a_src1 : a_dst1;
        float s = 0.f;
#pragma unroll
        for (int c = 0; c < 32; ++c)
            s += W1[k * 128 + h * 32 + c] * av[h * 32 + c];
        w1t[(128 + row8) * 128 + k] = f2bf(s * INV_LN2);
    } else if (g < 128 * 128 + 2048) {
        int e = g - (128 * 128 + 1024);
        w1t[(136 + (e >> 7)) * 128 + (e & 127)] = 0;
    }
}

// ---------------------------------------------------------------------------
// K1_FAT: blocks [0, nblk): BARRIER-FREE partition into fixed-capacity
// buckets: LDS chunk-hist -> ONE atomicAdd(&gcur[b],cnt) reservation per
// non-empty bucket (disjoint ranges, no ordering needed) -> bounds-guarded
// scatter into part[b*CAP ...]. Fully hidden under blocks [nblk, ...):
// MFMA GEMM [h1b | a_s1 | a_d1] = x @ [W1 | aw_s | aw_d] (9 n-tiles),
// A-fragments direct from global x, wsh reused for h1b output staging.
// (R4/R6 lesson: a 391-block spin barrier costs ~180us on this chip — the
// polling storm starves the serialized arrival RMWs. Fixed-cap buckets
// remove the need for the pre-scatter barrier entirely.)
// ---------------------------------------------------------------------------
__global__ __launch_bounds__(256) void k1_fat(const float* __restrict__ x,
                                              const unsigned short* __restrict__ w1t,
                                              unsigned short* __restrict__ h1b,
                                              float* __restrict__ a_s1,
                                              float* __restrict__ a_d1, int n,
                                              const int* __restrict__ e_src,
                                              const int* __restrict__ e_dst, int e,
                                              int nbuk, int nblk,
                                              int* __restrict__ gcur,
                                              unsigned int* __restrict__ part) {
    __shared__ unsigned short wsh[144 * XPAD];   // extended W^T bf16 (39.2 KB)
    const int tid = threadIdx.x;

    if (blockIdx.x < (unsigned)nblk) {
        // ================= partition (no barriers) =================
        int* lcur = (int*)wsh;                   // [MAXBUK] hist -> cursors
        const int bid = blockIdx.x;
        const int e0 = bid * CHUNK;
        const int e1 = min(e, e0 + CHUNK);
        for (int b = tid; b < nbuk; b += 256) lcur[b] = 0;
        __syncthreads();
        for (int k = e0 + tid; k < e1; k += 256)
            atomicAdd(&lcur[e_dst[k] >> BSH], 1);
        __syncthreads();
        // batch reservation into this bucket's FIXED region [b*CAP, (b+1)*CAP)
        for (int b = tid; b < nbuk; b += 256) {
            int c = lcur[b];
            if (c) lcur[b] = (b << CAPSH) + atomicAdd(&gcur[b], c);
        }
        __syncthreads();
        for (int k = e0 + tid; k < e1; k += 256) {
            int d = e_dst[k];
            int b = d >> BSH;
            int pos = atomicAdd(&lcur[b], 1);
            if (pos < ((b + 1) << CAPSH))        // 30-sigma guard, no OOB
                part[pos] = ((unsigned int)e_src[k] << 16) | (unsigned int)(d & 0xffff);
        }
        return;
    }

    // ================= GEMM path =================
    const int row0 = (blockIdx.x - nblk) * 64;
    // stage w1t -> wsh[n*XPAD+k]: 2304 ushort8 vector copies (9 per thread)
    {
        const bf16x8* w1v = (const bf16x8*)w1t;
#pragma unroll
        for (int ii = 0; ii < 9; ++ii) {
            int i = tid + ii * 256;
            int r = i >> 4, c = (i & 15) * 8;
            *(bf16x8*)&wsh[r * XPAD + c] = w1v[i];
        }
    }

    const int wave = tid >> 6;
    const int lane = tid & 63;
    const int quad = lane >> 4;
    const int l16 = lane & 15;

    // A fragments direct from global: row = row0 + wave*16 + l16,
    // k = ks*32 + quad*8 .. +7 (8 contiguous fp32 -> bf16x8)
    const int arow = row0 + wave * 16 + l16;
    const bool rowok = arow < n;
    const float* __restrict__ xr = x + (size_t)arow * 128;
    bf16x8 afrag[4];
#pragma unroll
    for (int ks = 0; ks < 4; ++ks) {
        float4 u = make_float4(0.f, 0.f, 0.f, 0.f), v = u;
        if (rowok) {
            u = *(const float4*)&xr[ks * 32 + quad * 8];
            v = *(const float4*)&xr[ks * 32 + quad * 8 + 4];
        }
        bf16x8 a;
        a[0] = (short)f2bf(u.x); a[1] = (short)f2bf(u.y);
        a[2] = (short)f2bf(u.z); a[3] = (short)f2bf(u.w);
        a[4] = (short)f2bf(v.x); a[5] = (short)f2bf(v.y);
        a[6] = (short)f2bf(v.z); a[7] = (short)f2bf(v.w);
        afrag[ks] = a;
    }
    __syncthreads();                      // wsh staged

    f32x4 acc[9];
#pragma unroll
    for (int t = 0; t < 9; ++t) acc[t] = (f32x4){0.f, 0.f, 0.f, 0.f};

#pragma unroll
    for (int t = 0; t < 9; ++t) {
#pragma unroll
        for (int ks = 0; ks < 4; ++ks) {
            bf16x8 bfrag = *(const bf16x8*)&wsh[(t * 16 + l16) * XPAD + ks * 32 + quad * 8];
            acc[t] = __builtin_amdgcn_mfma_f32_16x16x32_bf16(afrag[ks], bfrag, acc[t], 0, 0, 0);
        }
    }

    // tile 8: cols 0-3 = a_s heads, 4-7 = a_d (already INV_LN2-scaled)
#pragma unroll
    for (int r = 0; r < 4; ++r) {
        int gr = row0 + wave * 16 + quad * 4 + r;
        if (gr < n) {
            if (l16 < 4)      a_s1[gr * 4 + l16]       = acc[8][r];
            else if (l16 < 8) a_d1[gr * 4 + (l16 - 4)] = acc[8][r];
        }
    }

    // h1b store via LDS: reuse wsh (dead after MFMAs) as 64-row staging
    __syncthreads();                      // all waves done reading wsh
#pragma unroll
    for (int t = 0; t < 8; ++t)
#pragma unroll
        for (int r = 0; r < 4; ++r)
            wsh[(wave * 16 + quad * 4 + r) * XPAD + t * 16 + l16] = f2bf(acc[t][r]);
    __syncthreads();
#pragma unroll
    for (int i = 0; i < 8; ++i) {
        int idx = tid + i * 256;          // ushort4 index 0..2047 (32 per row)
        int r = idx >> 5;
        int c = (idx & 31) * 4;
        int gr = row0 + r;
        if (gr < n)
            *(ushort4*)&h1b[(size_t)gr * 128 + c] = *(ushort4*)&wsh[r * XPAD + c];
    }
}

// ---------------------------------------------------------------------------
// K3_AGG1: FUSED CSR finalize + layer-1 softmax-aggregation.
// One block per bucket, 512 threads (8 waves). Phase 1 = old kc_csr with the
// CSR kept in LDS (written through once, coalesced, for k4). Phase 2 = each
// wave processes 8 of the bucket's 64 nodes with the per-node loop (bulk
// unpredicated 16-slot iters + 4-slot mini-tail); edge ids read from LDS
// (broadcast, conflict-free). Saves the kc_csr dispatch + launch gap and the
// csr_src global re-read. 782 blocks at <=4 blocks/CU -> all co-resident.
// Fused epilogue: +bias, relu, layer-2 proj, layer-2 attn dots -> pk.
// ---------------------------------------------------------------------------
__global__ __launch_bounds__(512) void k3_agg1(
    const unsigned int* __restrict__ part, const int* __restrict__ gcur,
    const unsigned short* __restrict__ h1b, const float* __restrict__ a_s1,
    const float* __restrict__ a_d1, const float* __restrict__ b1,
    const float* __restrict__ W2, const float* __restrict__ a_src2,
    const float* __restrict__ a_dst2, float4* __restrict__ pk,
    int2* __restrict__ rsd, unsigned short* __restrict__ csr_src, int n) {
    __shared__ unsigned short lcsr[CAP];  // bucket CSR (4 KB)
    __shared__ int cnt[64];               // per-node degree (preserved)
    __shared__ int cur[64];               // scatter cursors
    __shared__ int lst[64];               // per-node exclusive start
    const int b = blockIdx.x;
    const int tid = threadIdx.x;
    const int eb = b << CAPSH;
    const int nE = min(gcur[b], CAP);

    // ---- phase 1: CSR finalize in LDS ----
    if (tid < 64) cnt[tid] = 0;
    __syncthreads();
    for (int k = tid; k < nE; k += 512)
        atomicAdd(&cnt[part[eb + k] & 63u], 1);
    __syncthreads();
    if (tid < 64) {                       // wave-0 exclusive scan of 64 counts
        int v = cnt[tid];
        int incl = v;
#pragma unroll
        for (int off = 1; off < 64; off <<= 1) {
            int t = __shfl_up(incl, off);
            if (tid >= off) incl += t;
        }
        int excl = incl - v;
        lst[tid] = excl;
        cur[tid] = excl;
        rsd[(b << BSH) + tid] = make_int2(eb + excl, v);   // for k4
    }
    __syncthreads();
    for (int k = tid; k < nE; k += 512) {
        unsigned int u = part[eb + k];
        int pos = atomicAdd(&cur[u & 63u], 1);
        lcsr[pos] = (unsigned short)(u >> 16);
    }
    __syncthreads();
    for (int k = tid; k < nE; k += 512)   // write-through for k4 (coalesced)
        csr_src[eb + k] = lcsr[k];

    // ---- phase 2: aggregation, wave wv handles nodes wv*8 .. wv*8+7 ----
    const int wv = tid >> 6;
    const int lane = tid & 63;
    const int q = lane >> 4;             // quarter: edge slot 0..3
    const int l16 = lane & 15;
    const int c0 = l16 * 8;              // 8 channels per lane
    const unsigned cb = (unsigned)l16 * 16u;   // byte offset within row
    const int head = l16 >> 2;           // 4 lanes per head
    const char* __restrict__ h1c = (const char*)h1b;

    for (int i = 0; i < 8; ++i) {
        const int node = (b << BSH) + (wv << 3) + i;   // wave-uniform
        if (node >= n) continue;
        const int nl = node & 63;
        const int ls = lst[nl];
        const int deg = cnt[nl];
        const float ad = a_d1[node * 4 + head];

        float dnm = 0.f;
        float acc[8] = {};
        const int nfull = deg >> 4;
        const int dm1 = deg - 1;
        int j = q;
        for (int it = 0; it < nfull; ++it, j += 16) {   // unpredicated full iters
            unsigned s0 = (unsigned)lcsr[ls + j];
            unsigned s1 = (unsigned)lcsr[ls + j + 4];
            unsigned s2 = (unsigned)lcsr[ls + j + 8];
            unsigned s3 = (unsigned)lcsr[ls + j + 12];
            float as0 = a_s1[(s0 << 2) + head];
            float as1 = a_s1[(s1 << 2) + head];
            float as2 = a_s1[(s2 << 2) + head];
            float as3 = a_s1[(s3 << 2) + head];
            uint4 g0 = *(const uint4*)(h1c + ((s0 << 8) + cb));
            uint4 g1 = *(const uint4*)(h1c + ((s1 << 8) + cb));
            uint4 g2 = *(const uint4*)(h1c + ((s2 << 8) + cb));
            uint4 g3 = *(const uint4*)(h1c + ((s3 << 8) + cb));
            float p0 = exp2lrelu(as0 + ad);
            float p1 = exp2lrelu(as1 + ad);
            float p2 = exp2lrelu(as2 + ad);
            float p3 = exp2lrelu(as3 + ad);
            dnm += (p0 + p1) + (p2 + p3);
            float2 v0a = bfpair(g0.x), v0b = bfpair(g0.y), v0c = bfpair(g0.z), v0d = bfpair(g0.w);
            float2 v1a = bfpair(g1.x), v1b = bfpair(g1.y), v1c = bfpair(g1.z), v1d = bfpair(g1.w);
            float2 v2a = bfpair(g2.x), v2b = bfpair(g2.y), v2c = bfpair(g2.z), v2d = bfpair(g2.w);
            float2 v3a = bfpair(g3.x), v3b = bfpair(g3.y), v3c = bfpair(g3.z), v3d = bfpair(g3.w);
            acc[0] += (p0 * v0a.x + p1 * v1a.x) + (p2 * v2a.x + p3 * v3a.x);
            acc[1] += (p0 * v0a.y + p1 * v1a.y) + (p2 * v2a.y + p3 * v3a.y);
            acc[2] += (p0 * v0b.x + p1 * v1b.x) + (p2 * v2b.x + p3 * v3b.x);
            acc[3] += (p0 * v0b.y + p1 * v1b.y) + (p2 * v2b.y + p3 * v3b.y);
            acc[4] += (p0 * v0c.x + p1 * v1c.x) + (p2 * v2c.x + p3 * v3c.x);
            acc[5] += (p0 * v0c.y + p1 * v1c.y) + (p2 * v2c.y + p3 * v3c.y);
            acc[6] += (p0 * v0d.x + p1 * v1d.x) + (p2 * v2d.x + p3 * v3d.x);
            acc[7] += (p0 * v0d.y + p1 * v1d.y) + (p2 * v2d.y + p3 * v3d.y);
        }
        for (int t = nfull << 4; t < deg; t += 4) {     // 4-slot mini-tail
            const int slot = t + q;
            const bool ok = slot < deg;
            unsigned s0 = (unsigned)lcsr[ls + min(slot, dm1)];
            float as0 = a_s1[(s0 << 2) + head];
            uint4 g0 = make_uint4(0, 0, 0, 0);
            if (ok) g0 = *(const uint4*)(h1c + ((s0 << 8) + cb));
            float p0 = ok ? exp2lrelu(as0 + ad) : 0.f;
            dnm += p0;
            float2 va = bfpair(g0.x), vb = bfpair(g0.y), vc = bfpair(g0.z), vd = bfpair(g0.w);
            acc[0] += p0 * va.x;  acc[1] += p0 * va.y;
            acc[2] += p0 * vb.x;  acc[3] += p0 * vb.y;
            acc[4] += p0 * vc.x;  acc[5] += p0 * vc.y;
            acc[6] += p0 * vd.x;  acc[7] += p0 * vd.y;
        }
        // combine quarters
        dnm += __shfl_xor(dnm, 16);
        dnm += __shfl_xor(dnm, 32);
#pragma unroll
        for (int k = 0; k < 8; ++k) {
            acc[k] += __shfl_xor(acc[k], 16);
            acc[k] += __shfl_xor(acc[k], 32);
        }
        // self-loop (uniform across quarters)
        {
            float p = exp2lrelu(a_s1[node * 4 + head] + ad);
            uint4 gs = *(const uint4*)(h1c + (((unsigned)node << 8) + cb));
            float2 ha = bfpair(gs.x), hb = bfpair(gs.y), hc = bfpair(gs.z), hd2 = bfpair(gs.w);
            dnm += p;
            acc[0] += p * ha.x;  acc[1] += p * ha.y;
            acc[2] += p * hb.x;  acc[3] += p * hb.y;
            acc[4] += p * hc.x;  acc[5] += p * hc.y;
            acc[6] += p * hd2.x; acc[7] += p * hd2.y;
        }
        float inv = 1.f / (dnm + 1e-16f);
        float r[8];
        float4 bva = *(const float4*)&b1[c0];
        float4 bvb = *(const float4*)&b1[c0 + 4];
        r[0] = fmaxf(acc[0] * inv + bva.x, 0.f);
        r[1] = fmaxf(acc[1] * inv + bva.y, 0.f);
        r[2] = fmaxf(acc[2] * inv + bva.z, 0.f);
        r[3] = fmaxf(acc[3] * inv + bva.w, 0.f);
        r[4] = fmaxf(acc[4] * inv + bvb.x, 0.f);
        r[5] = fmaxf(acc[5] * inv + bvb.y, 0.f);
        r[6] = fmaxf(acc[6] * inv + bvb.z, 0.f);
        r[7] = fmaxf(acc[7] * inv + bvb.w, 0.f);

        // fused layer-2 projection
        float p0 = 0.f, p1 = 0.f;
#pragma unroll
        for (int k = 0; k < 4; ++k) {
            float4 w = *(const float4*)&W2[c0 * 2 + k * 4];
            p0 += r[2 * k] * w.x + r[2 * k + 1] * w.z;
            p1 += r[2 * k] * w.y + r[2 * k + 1] * w.w;
        }
#pragma unroll
        for (int off = 1; off < 16; off <<= 1) {
            p0 += __shfl_xor(p0, off);
            p1 += __shfl_xor(p1, off);
        }
        if (lane == 0) {
            pk[node] = make_float4(p0, p1,
                                   (p0 * a_src2[0] + p1 * a_src2[1]) * INV_LN2,
                                   (p0 * a_dst2[0] + p1 * a_dst2[1]) * INV_LN2);
        }
    }
}

// ---------------------------------------------------------------------------
// K4: layer-2 softmax-aggregation (1 head, 2 ch) + bias + log_softmax.
// ---------------------------------------------------------------------------
__global__ __launch_bounds__(256) void k4_agg2(
    const float4* __restrict__ pk, const int2* __restrict__ rsd,
    const unsigned short* __restrict__ csr_src, const float* __restrict__ b2,
    float* __restrict__ out, int n) {
    const int g = blockIdx.x * blockDim.x + threadIdx.x;
    const int lane = threadIdx.x & 63;
    const int node = (g >> 6) * 4 + (lane >> 4);
    const int l16 = lane & 15;
    if (node >= n) return;
    const int2 rd = rsd[node];
    const int rs = rd.x;
    const int deg = rd.y;
    const float4 me = pk[node];
    const float ad = me.w;

    float dnm = 0.f, a0 = 0.f, a1 = 0.f;
    for (int j = l16; j < deg; j += 16) {
        int s = (int)csr_src[rs + j];
        float4 qv = pk[s];
        float p = exp2lrelu(qv.z + ad);
        dnm += p;
        a0 += p * qv.x;
        a1 += p * qv.y;
    }
    if (l16 == 0) {   // self-loop
        float p = exp2lrelu(me.z + ad);
        dnm += p;
        a0 += p * me.x;
        a1 += p * me.y;
    }
#pragma unroll
    for (int off = 1; off < 16; off <<= 1) {
        dnm += __shfl_xor(dnm, off);
        a0 += __shfl_xor(a0, off);
        a1 += __shfl_xor(a1, off);
    }
    if (l16 == 0) {
        float inv = 1.f / (dnm + 1e-16f);
        float o0 = a0 * inv + b2[0];
        float o1 = a1 * inv + b2[1];
        float m2 = fmaxf(o0, o1);
        float lse = m2 + logf(__expf(o0 - m2) + __expf(o1 - m2));
        out[node * 2 + 0] = o0 - lse;
        out[node * 2 + 1] = o1 - lse;
    }
}

// ---------------------------------------------------------------------------
extern "C" void kernel_launch(void* const* d_in, const int* in_sizes, int n_in,
                              void* d_out, int out_size, void* d_ws, size_t ws_size,
                              hipStream_t stream) {
    const float* x      = (const float*)d_in[0];
    const int*   ei     = (const int*)d_in[1];
    const float* W1     = (const float*)d_in[2];
    const float* a_src1 = (const float*)d_in[3];
    const float* a_dst1 = (const float*)d_in[4];
    const float* b1     = (const float*)d_in[5];
    const float* W2     = (const float*)d_in[6];
    const float* a_src2 = (const float*)d_in[7];
    const float* a_dst2 = (const float*)d_in[8];
    const float* b2     = (const float*)d_in[9];
    float* out = (float*)d_out;

    const int N = in_sizes[0] / 128;
    const int E = in_sizes[1] / 2;
    const int* e_src = ei;        // edge_index[0]
    const int* e_dst = ei + E;    // edge_index[1]

    const int NBUK = (N + BUKSZ - 1) >> BSH;     // 782 for N=50000
    const int nblk = (E + CHUNK - 1) / CHUNK;    // 391 for E=800000
    const int gemmBlocks = (N + 63) / 64;        // 782

    // ---- workspace carve (256B aligned)
    char* p = (char*)d_ws;
    auto alloc = [&](size_t bytes) -> void* {
        void* r = (void*)p;
        p += (bytes + 255) & ~(size_t)255;
        return r;
    };
    unsigned short* h1b   = (unsigned short*)alloc((size_t)N * 128 * 2);
    float*          a_s1  = (float*)alloc((size_t)N * 4 * 4);
    float*          a_d1  = (float*)alloc((size_t)N * 4 * 4);
    float4*         pk    = (float4*)alloc((size_t)N * 16);
    unsigned short* w1t   = (unsigned short*)alloc((size_t)144 * 128 * 2);
    int*            gcur  = (int*)alloc((size_t)NBUK * 4);
    unsigned int*   part  = (unsigned int*)alloc((size_t)NBUK * CAP * 4);
    int2*           rsd   = (int2*)alloc((size_t)(NBUK << BSH) * 8);
    unsigned short* csr_src = (unsigned short*)alloc((size_t)NBUK * CAP * 2);

    k0_prep<<<72, 256, 0, stream>>>(W1, a_src1, a_dst1, w1t, gcur, NBUK);
    k1_fat<<<nblk + gemmBlocks, 256, 0, stream>>>(x, w1t, h1b, a_s1, a_d1, N,
                                                  e_src, e_dst, E, NBUK, nblk,
                                                  gcur, part);
    k3_agg1<<<NBUK, 512, 0, stream>>>(part, gcur, h1b, a_s1, a_d1,
                                      b1, W2, a_src2, a_dst2, pk, rsd, csr_src, N);
    k4_agg2<<<((N + 3) / 4 * 64 + 255) / 256, 256, 0, stream>>>(pk, rsd, csr_src,
                                                                b2, out, N);
}